// Round 1
// baseline (204.898 us; speedup 1.0000x reference)
//
#include <hip/hip_runtime.h>
#include <hip/hip_bf16.h>

#define N_NODES 100000
#define D_IN 64
#define D_HID 128
#define D_OUT 64

// ---------------------------------------------------------------------------
// Kernel 1: degree histogram over edge_dst (int32 indices)
// ---------------------------------------------------------------------------
__global__ __launch_bounds__(256) void degree_kernel(const int* __restrict__ dst,
                                                     int* __restrict__ deg, int E) {
    int i = blockIdx.x * blockDim.x + threadIdx.x;
    int stride = gridDim.x * blockDim.x;
    for (; i < E; i += stride) {
        atomicAdd(&deg[dst[i]], 1);
    }
}

// ---------------------------------------------------------------------------
// Kernel 2: precompute Wc = W1@W2 [64x64], bc = b1@W2 [64]
// W1: [64,128] row-major (in,out). W2: [128,64] row-major.
// ---------------------------------------------------------------------------
__global__ __launch_bounds__(256) void precompute_kernel(const float* __restrict__ W1,
                                                         const float* __restrict__ b1,
                                                         const float* __restrict__ W2,
                                                         float* __restrict__ Wc,
                                                         float* __restrict__ bc) {
    int idx = blockIdx.x * blockDim.x + threadIdx.x;
    if (idx < 64 * 64) {
        int i = idx >> 6;     // row of W1
        int j = idx & 63;     // col of W2
        float s = 0.f;
        #pragma unroll 8
        for (int k = 0; k < D_HID; ++k) {
            s = fmaf(W1[i * D_HID + k], W2[k * D_OUT + j], s);
        }
        Wc[idx] = s;
    } else if (idx < 64 * 64 + 64) {
        int j = idx - 64 * 64;
        float s = 0.f;
        #pragma unroll 8
        for (int k = 0; k < D_HID; ++k) {
            s = fmaf(b1[k], W2[k * D_OUT + j], s);
        }
        bc[j] = s;
    }
}

// ---------------------------------------------------------------------------
// Kernel 3: out[n][j] = (1+deg[n]) * (x[n,:] @ Wc[:,j] + bc[j]) + b2[j]
// One wave per node-iteration; lane j holds Wc[:,j] in 64 VGPRs.
// ---------------------------------------------------------------------------
__global__ __launch_bounds__(256) void gnn_main_kernel(const float* __restrict__ x,
                                                       const int* __restrict__ deg,
                                                       const float* __restrict__ Wc,
                                                       const float* __restrict__ bc,
                                                       const float* __restrict__ b2,
                                                       float* __restrict__ out, int N) {
    const int lane = threadIdx.x & 63;
    const int wave_id = blockIdx.x * (blockDim.x >> 6) + (threadIdx.x >> 6);
    const int nwaves = gridDim.x * (blockDim.x >> 6);

    // Lane j caches column j of Wc (64 VGPRs). All waves read the same 16 KB
    // -> served from L2/L3 after first touch.
    float wc[64];
    #pragma unroll
    for (int k = 0; k < 64; ++k) wc[k] = Wc[k * 64 + lane];
    const float bcj = bc[lane];
    const float b2j = b2[lane];

    for (int n = wave_id; n < N; n += nwaves) {
        float xv = x[(size_t)n * 64 + lane];   // coalesced 256 B per wave
        float acc = 0.f;
        #pragma unroll
        for (int k = 0; k < 64; ++k) {
            acc = fmaf(__shfl(xv, k), wc[k], acc);  // readlane broadcast
        }
        float s = 1.0f + (float)deg[n];         // wave-uniform load, HW broadcast
        out[(size_t)n * 64 + lane] = fmaf(s, acc + bcj, b2j);
    }
}

// ---------------------------------------------------------------------------
extern "C" void kernel_launch(void* const* d_in, const int* in_sizes, int n_in,
                              void* d_out, int out_size, void* d_ws, size_t ws_size,
                              hipStream_t stream) {
    const float* x  = (const float*)d_in[0];
    const int*   ei = (const int*)d_in[1];      // [2, E] int32 per harness convention
    const float* W1 = (const float*)d_in[2];
    const float* b1 = (const float*)d_in[3];
    const float* W2 = (const float*)d_in[4];
    const float* b2 = (const float*)d_in[5];
    float* out = (float*)d_out;

    const int E = in_sizes[1] / 2;
    const int N = N_NODES;
    const int* edge_dst = ei + E;               // second row of edge_index

    // Workspace layout: [deg: N int32][Wc: 64x64 f32][bc: 64 f32]
    char* ws = (char*)d_ws;
    int*   deg = (int*)ws;
    size_t deg_bytes = (size_t)N * sizeof(int);
    size_t wc_off = (deg_bytes + 255) & ~(size_t)255;
    float* Wc = (float*)(ws + wc_off);
    float* bc = Wc + 64 * 64;

    // deg must start at zero (ws is poisoned to 0xAA before every launch).
    hipMemsetAsync(deg, 0, deg_bytes, stream);

    degree_kernel<<<512, 256, 0, stream>>>(edge_dst, deg, E);
    precompute_kernel<<<(64 * 64 + 64 + 255) / 256, 256, 0, stream>>>(W1, b1, W2, Wc, bc);
    gnn_main_kernel<<<512, 256, 0, stream>>>(x, deg, Wc, bc, b2, out, N);
}

// Round 4
// 140.820 us; speedup vs baseline: 1.4550x; 1.4550x over previous
//
// Round 3 resubmit: identical to Round 2 source (untested due to two
// consecutive "MI355X container failed twice" broker errors — no compile or
// runtime diagnostic was produced, so the MFMA theory is untested, not
// falsified). OOB/alignment re-audited: all vector loads 16B-aligned, all
// indices in range, no tail tiles (100000 % 16 == 0).
#include <hip/hip_runtime.h>
#include <hip/hip_bf16.h>

#define N_NODES 100000
#define D_IN 64
#define D_HID 128
#define D_OUT 64

typedef __attribute__((ext_vector_type(8))) short bf16x8;
typedef __attribute__((ext_vector_type(4))) float f32x4;
typedef __attribute__((ext_vector_type(4))) int i32x4;

__device__ inline short f2bf(float f) {
    __hip_bfloat16 h = __float2bfloat16(f);
    return __builtin_bit_cast(short, h);
}

// ---------------------------------------------------------------------------
// Kernel 1: degree histogram over edge_dst (int32), int4-vectorized loads
// ---------------------------------------------------------------------------
__global__ __launch_bounds__(256) void degree_kernel(const int* __restrict__ dst,
                                                     int* __restrict__ deg, int E) {
    int i = blockIdx.x * blockDim.x + threadIdx.x;
    int i4 = i * 4;
    if (i4 + 3 < E) {
        i32x4 v = *(const i32x4*)(dst + i4);
        atomicAdd(&deg[v.x], 1);
        atomicAdd(&deg[v.y], 1);
        atomicAdd(&deg[v.z], 1);
        atomicAdd(&deg[v.w], 1);
    } else {
        for (int e = i4; e < E; ++e) atomicAdd(&deg[dst[e]], 1);
    }
}

// ---------------------------------------------------------------------------
// Kernel 2: WcT[j][i] = bf16( (W1@W2)[i][j] ), bc[j] = b1@W2[:,j]
// W1: [64,128] row-major. W2: [128,64] row-major.
// ---------------------------------------------------------------------------
__global__ __launch_bounds__(256) void precompute_kernel(const float* __restrict__ W1,
                                                         const float* __restrict__ b1,
                                                         const float* __restrict__ W2,
                                                         unsigned short* __restrict__ WcT,
                                                         float* __restrict__ bc) {
    int idx = blockIdx.x * blockDim.x + threadIdx.x;
    if (idx < 64 * 64) {
        int i = idx >> 6;     // input dim (k of final GEMM)
        int j = idx & 63;     // output col
        float s = 0.f;
        #pragma unroll 8
        for (int k = 0; k < D_HID; ++k)
            s = fmaf(W1[i * D_HID + k], W2[k * D_OUT + j], s);
        WcT[j * 64 + i] = (unsigned short)f2bf(s);   // store transposed [col][k]
    } else if (idx < 64 * 64 + 64) {
        int j = idx - 64 * 64;
        float s = 0.f;
        #pragma unroll 8
        for (int k = 0; k < D_HID; ++k)
            s = fmaf(b1[k], W2[k * D_OUT + j], s);
        bc[j] = s;
    }
}

// ---------------------------------------------------------------------------
// Kernel 3 (MFMA): out[n][j] = (1+deg[n]) * (x[n,:]@Wc[:,j] + bc[j]) + b2[j]
// One wave per 16-node tile. mfma_f32_16x16x32_bf16:
//   A-frag: lane holds A[m=lane&15][k=(lane>>4)*8 + j], j=0..7
//   B-frag: lane holds B[k=(lane>>4)*8 + j][n=lane&15]
//   C/D:    lane holds D[row=(lane>>4)*4 + reg][col=lane&15]
// ---------------------------------------------------------------------------
__global__ __launch_bounds__(256) void gnn_main_mfma(const float* __restrict__ x,
                                                     const int* __restrict__ deg,
                                                     const unsigned short* __restrict__ WcT,
                                                     const float* __restrict__ bc,
                                                     const float* __restrict__ b2,
                                                     float* __restrict__ out, int N) {
    const int lane = threadIdx.x & 63;
    const int wave = (int)((blockIdx.x * blockDim.x + threadIdx.x) >> 6);
    const int nwaves = (int)((gridDim.x * blockDim.x) >> 6);
    const int quad = lane >> 4;     // 0..3
    const int l15 = lane & 15;

    // B fragments: 4 col-tiles x 2 k-chunks, loaded once (16 KB shared via L2).
    // WcT is [col][k] so each fragment is 8 contiguous bf16 = one 16B load.
    bf16x8 bfrag[4][2];
    #pragma unroll
    for (int ct = 0; ct < 4; ++ct)
        #pragma unroll
        for (int kc = 0; kc < 2; ++kc)
            bfrag[ct][kc] = *(const bf16x8*)(WcT + (16 * ct + l15) * 64 + 32 * kc + quad * 8);

    float bcv[4], b2v[4];
    #pragma unroll
    for (int ct = 0; ct < 4; ++ct) {
        bcv[ct] = bc[16 * ct + l15];
        b2v[ct] = b2[16 * ct + l15];
    }

    const int ntiles = N >> 4;      // N = 100000 -> 6250 exact
    for (int t = wave; t < ntiles; t += nwaves) {
        const int n0 = t << 4;
        const int row = n0 + l15;
        // A fragments: 8 consecutive fp32 of x-row -> 8 bf16
        bf16x8 afrag[2];
        #pragma unroll
        for (int kc = 0; kc < 2; ++kc) {
            const float* p = x + (size_t)row * 64 + 32 * kc + quad * 8;
            f32x4 lo = *(const f32x4*)p;
            f32x4 hi = *(const f32x4*)(p + 4);
            bf16x8 a;
            #pragma unroll
            for (int j = 0; j < 4; ++j) { a[j] = f2bf(lo[j]); a[4 + j] = f2bf(hi[j]); }
            afrag[kc] = a;
        }

        f32x4 acc[4] = {{0.f,0.f,0.f,0.f},{0.f,0.f,0.f,0.f},{0.f,0.f,0.f,0.f},{0.f,0.f,0.f,0.f}};
        #pragma unroll
        for (int ct = 0; ct < 4; ++ct) {
            acc[ct] = __builtin_amdgcn_mfma_f32_16x16x32_bf16(afrag[0], bfrag[ct][0], acc[ct], 0, 0, 0);
            acc[ct] = __builtin_amdgcn_mfma_f32_16x16x32_bf16(afrag[1], bfrag[ct][1], acc[ct], 0, 0, 0);
        }

        // Epilogue: row rn = n0 + quad*4 + r, col = 16*ct + l15
        #pragma unroll
        for (int r = 0; r < 4; ++r) {
            const int rn = n0 + quad * 4 + r;
            const float s = 1.0f + (float)deg[rn];
            #pragma unroll
            for (int ct = 0; ct < 4; ++ct)
                out[(size_t)rn * 64 + 16 * ct + l15] = fmaf(s, acc[ct][r] + bcv[ct], b2v[ct]);
        }
    }
}

// ---------------------------------------------------------------------------
extern "C" void kernel_launch(void* const* d_in, const int* in_sizes, int n_in,
                              void* d_out, int out_size, void* d_ws, size_t ws_size,
                              hipStream_t stream) {
    const float* x  = (const float*)d_in[0];
    const int*   ei = (const int*)d_in[1];      // [2, E] int32
    const float* W1 = (const float*)d_in[2];
    const float* b1 = (const float*)d_in[3];
    const float* W2 = (const float*)d_in[4];
    const float* b2 = (const float*)d_in[5];
    float* out = (float*)d_out;

    const int E = in_sizes[1] / 2;
    const int N = N_NODES;
    const int* edge_dst = ei + E;

    // Workspace: [deg: N int32][WcT: 64x64 bf16][bc: 64 f32]
    char* ws = (char*)d_ws;
    int* deg = (int*)ws;
    size_t deg_bytes = (size_t)N * sizeof(int);
    size_t wct_off = (deg_bytes + 255) & ~(size_t)255;
    unsigned short* WcT = (unsigned short*)(ws + wct_off);
    float* bc = (float*)(ws + wct_off + 64 * 64 * sizeof(unsigned short));

    hipMemsetAsync(deg, 0, deg_bytes, stream);

    int deg_threads = (E + 3) / 4;
    degree_kernel<<<(deg_threads + 255) / 256, 256, 0, stream>>>(edge_dst, deg, E);
    precompute_kernel<<<(64 * 64 + 64 + 255) / 256, 256, 0, stream>>>(W1, b1, W2, WcT, bc);
    gnn_main_mfma<<<512, 256, 0, stream>>>(x, deg, WcT, bc, b2, out, N);
}